// Round 6
// baseline (30.992 us; speedup 1.0000x reference)
//
#include <hip/hip_runtime.h>
#include <hip/hip_bf16.h>

// DecoderBlock: block-sparse masked linear (8 GEMMs M=256,N=1024,K=1024)
// + BatchNorm1d (batch stats; bias cancels exactly) + Swish.
// FUSED: block = full batch (256 rows) x 32 features -> BN stats block-local.
// grid 256 = 8 g x 32 nt; g=bid&7 -> XCD-local x slice (512KB bf16 in L2).
// Round-6 lever: 73KB LDS (A double-buffer) -> 2 blocks/CU, 2 waves/SIMD;
// step body reordered so double-buffering is race-free; latency hidden by TLP.

typedef float  f32x4  __attribute__((ext_vector_type(4)));
typedef short  short8 __attribute__((ext_vector_type(8)));
typedef unsigned short u16x8 __attribute__((ext_vector_type(8)));

static __device__ __forceinline__ unsigned short f2bf(float f) {
    unsigned int u = __float_as_uint(f);
    u += 0x7FFFu + ((u >> 16) & 1u);          // RNE (inputs finite)
    return (unsigned short)(u >> 16);
}

#define GLL(gp, lp) __builtin_amdgcn_global_load_lds( \
    (const __attribute__((address_space(1))) unsigned int*)(gp), \
    (__attribute__((address_space(3))) unsigned int*)(lp), 16, 0, 0)

// ---------------- x f32 -> bf16 (12 MB traffic; result L2/L3-resident) ----------------
__global__ __launch_bounds__(256) void conv_kernel(const float* __restrict__ x,
                                                   unsigned short* __restrict__ xb) {
    const int base = blockIdx.x * 1024 + threadIdx.x;
#pragma unroll
    for (int i = 0; i < 4; ++i) {
        const int cid = base + i * 256;               // 8-float chunk id
        const f32x4 a = *(const f32x4*)(x + (size_t)cid * 8);
        const f32x4 b = *(const f32x4*)(x + (size_t)cid * 8 + 4);
        u16x8 v;
        v[0] = f2bf(a[0]); v[1] = f2bf(a[1]); v[2] = f2bf(a[2]); v[3] = f2bf(a[3]);
        v[4] = f2bf(b[0]); v[5] = f2bf(b[1]); v[6] = f2bf(b[2]); v[7] = f2bf(b[3]);
        *(u16x8*)(xb + (size_t)cid * 8) = v;
    }
}

// ---------------- fused GEMM + BN + Swish ----------------
// Block: M=256 x N=32, K=1024, BK=64 (16 steps). 4 waves stacked in M (64 rows).
// A: [256][64] bf16 LDS x2, GLL w/ source pre-swizzle (c ^= r&7).
// B: [32][64] bf16 LDS x2, reg-staged f32->bf16, swizzled ds_write.
// Step body: WWRITE(st); vmcnt(0); lgkmcnt(0); barrier; ISSUE(st+1); COMPUTE(st)
//  -> per inter-barrier region, writers touch parity st+1, readers parity st.
__global__ __launch_bounds__(256) void fused_kernel(
    const unsigned short* __restrict__ xb, const float* __restrict__ W,
    const float* __restrict__ gamma, const float* __restrict__ beta,
    float* __restrict__ out)
{
    __shared__ __align__(16) char ldsA[2][32768];
    __shared__ __align__(16) char ldsB[2][4096];
    __shared__ float wps1[4][32], wps2[4][32];
    __shared__ float sa[32], sb[32];

    const int bid = blockIdx.x;
    const int g   = bid & 7;               // channel group -> XCD
    const int nt  = bid >> 3;              // 0..31
    const int o   = g * 4 + (nt >> 3);
    const int f0  = (nt & 7) * 32;
    const int gcol0 = o * 256 + f0;

    const int t    = threadIdx.x;
    const int wave = t >> 6;
    const int lane = t & 63;
    const int lr   = lane & 15;
    const int kq   = lane >> 4;

    f32x4 acc[4][2];
    const f32x4 zero = {0.f, 0.f, 0.f, 0.f};
#pragma unroll
    for (int i = 0; i < 4; ++i) { acc[i][0] = zero; acc[i][1] = zero; }

    f32x4 breg[2][2];

    auto ISSUE = [&](int st) {             // B f32 -> regs first, then A via GLL
        const int cp = st >> 2, kc = (st & 3) * 64;
        const float* bsrc = W + ((size_t)((o * 32 + g * 4 + cp) * 256 + f0)) * 256 + kc
                              + (size_t)(t >> 3) * 256 + (t & 7) * 8;
        breg[st & 1][0] = *(const f32x4*)bsrc;
        breg[st & 1][1] = *(const f32x4*)(bsrc + 4);
        const int kk = st * 64;
        const unsigned short* asrc = xb + g * 1024 + kk;
        char* Ab = ldsA[st & 1];
#pragma unroll
        for (int i = 0; i < 8; ++i) {
            const int cid = i * 256 + t;
            const int r = cid >> 3, c = cid & 7;
            GLL(asrc + (size_t)r * 8192 + (c ^ (r & 7)) * 8, Ab + cid * 16);
        }
    };
    auto WRITEB = [&](int st) {            // convert + swizzled ds_write
        const int n = t >> 3, c = t & 7;
        short8 v;
        v[0] = (short)f2bf(breg[st & 1][0][0]); v[1] = (short)f2bf(breg[st & 1][0][1]);
        v[2] = (short)f2bf(breg[st & 1][0][2]); v[3] = (short)f2bf(breg[st & 1][0][3]);
        v[4] = (short)f2bf(breg[st & 1][1][0]); v[5] = (short)f2bf(breg[st & 1][1][1]);
        v[6] = (short)f2bf(breg[st & 1][1][2]); v[7] = (short)f2bf(breg[st & 1][1][3]);
        *(short8*)(ldsB[st & 1] + n * 128 + ((c ^ (n & 7)) * 16)) = v;
    };
    auto COMPUTE = [&](int st) {
        const char* Ab = ldsA[st & 1];
        const char* Bb = ldsB[st & 1];
#pragma unroll
        for (int ks = 0; ks < 2; ++ks) {
            short8 af[4], bfr[2];
#pragma unroll
            for (int i = 0; i < 4; ++i) {
                const int ra = wave * 64 + i * 16 + lr;
                af[i] = *(const short8*)(Ab + ra * 128 + (((ks * 4 + kq) ^ (ra & 7)) * 16));
            }
#pragma unroll
            for (int j = 0; j < 2; ++j) {
                const int n = j * 16 + lr;
                bfr[j] = *(const short8*)(Bb + n * 128 + (((ks * 4 + kq) ^ (n & 7)) * 16));
            }
#pragma unroll
            for (int i = 0; i < 4; ++i)
#pragma unroll
                for (int j = 0; j < 2; ++j)
                    acc[i][j] = __builtin_amdgcn_mfma_f32_16x16x32_bf16(af[i], bfr[j], acc[i][j], 0, 0, 0);
        }
    };

    ISSUE(0);
#pragma unroll
    for (int st = 0; st < 16; ++st) {
        WRITEB(st);                                        // compiler waits breg(st)
        asm volatile("s_waitcnt vmcnt(0)" ::: "memory");   // A(st) landed (issued 1 phase ago)
        asm volatile("s_waitcnt lgkmcnt(0)" ::: "memory"); // B(st) ds_writes visible
        __builtin_amdgcn_s_barrier();
        if (st < 15) ISSUE(st + 1);                        // writers: parity st+1 only
        COMPUTE(st);                                       // readers: parity st only
    }

    // ---------------- fused BN + Swish epilogue ----------------
    float s1[2] = {0.f, 0.f}, s2[2] = {0.f, 0.f};
#pragma unroll
    for (int i = 0; i < 4; ++i)
#pragma unroll
        for (int j = 0; j < 2; ++j)
#pragma unroll
            for (int r = 0; r < 4; ++r) {
                const float v = acc[i][j][r];
                s1[j] += v; s2[j] += v * v;
            }
#pragma unroll
    for (int j = 0; j < 2; ++j) {          // reduce across kq groups (lanes sharing lr)
        s1[j] += __shfl_xor(s1[j], 16); s2[j] += __shfl_xor(s2[j], 16);
        s1[j] += __shfl_xor(s1[j], 32); s2[j] += __shfl_xor(s2[j], 32);
    }
    if (kq == 0) {
#pragma unroll
        for (int j = 0; j < 2; ++j) {
            wps1[wave][j * 16 + lr] = s1[j];
            wps2[wave][j * 16 + lr] = s2[j];
        }
    }
    __syncthreads();
    if (t < 32) {
        float a1 = wps1[0][t] + wps1[1][t] + wps1[2][t] + wps1[3][t];
        float a2 = wps2[0][t] + wps2[1][t] + wps2[2][t] + wps2[3][t];
        const float mean = a1 * (1.0f / 256.0f);
        const float var  = a2 * (1.0f / 256.0f) - mean * mean;   // biased (jnp.var)
        const float istd = rsqrtf(var + 1e-5f);
        const float ga = gamma[gcol0 + t];
        sa[t] = ga * istd;
        sb[t] = beta[gcol0 + t] - mean * ga * istd;
    }
    __syncthreads();

    // apply affine + swish; C/D layout col=lane&15, row=(lane>>4)*4+reg
#pragma unroll
    for (int i = 0; i < 4; ++i) {
        const int row0 = wave * 64 + i * 16 + kq * 4;
#pragma unroll
        for (int j = 0; j < 2; ++j) {
            const int col = j * 16 + lr;
            const float a = sa[col], b2 = sb[col];
#pragma unroll
            for (int r = 0; r < 4; ++r) {
                const float z = a * acc[i][j][r] + b2;
                out[(size_t)(row0 + r) * 8192 + gcol0 + col] = z / (1.0f + expf(-z));
            }
        }
    }
}

extern "C" void kernel_launch(void* const* d_in, const int* in_sizes, int n_in,
                              void* d_out, int out_size, void* d_ws, size_t ws_size,
                              hipStream_t stream) {
    const float* x     = (const float*)d_in[0];
    const float* W     = (const float*)d_in[1];
    // d_in[2] = bias: cancelled exactly by BN mean subtraction -> unused
    const float* gamma = (const float*)d_in[3];
    const float* beta  = (const float*)d_in[4];
    // d_in[5] = mask: implicit in block structure -> unused
    float* out = (float*)d_out;

    unsigned short* xb = (unsigned short*)d_ws;   // 4MB bf16 x

    conv_kernel<<<256, 256, 0, stream>>>(x, xb);
    fused_kernel<<<256, 256, 0, stream>>>(xb, W, gamma, beta, out);
}

// Round 7
// 28.932 us; speedup vs baseline: 1.0712x; 1.0712x over previous
//
#include <hip/hip_runtime.h>
#include <hip/hip_bf16.h>

// DecoderBlock: block-sparse masked linear (8 GEMMs M=256,N=1024,K=1024)
// + BatchNorm1d (batch stats; bias cancels exactly) + Swish.
// FUSED: block = full batch (256 rows) x 32 features -> BN stats block-local.
// grid 256 = 8 g x 32 nt; g=bid&7 -> XCD-local x slice (512KB bf16 in L2).
// Round-7: 2 blocks/CU (73KB LDS, A dbuf) + W prefetch ring depth 4 with
// counted vmcnt(2) at barriers (W never drained fresh; A drained after ~L2 lat).

typedef float  f32x4  __attribute__((ext_vector_type(4)));
typedef short  short8 __attribute__((ext_vector_type(8)));
typedef unsigned short u16x8 __attribute__((ext_vector_type(8)));

static __device__ __forceinline__ unsigned short f2bf(float f) {
    unsigned int u = __float_as_uint(f);
    u += 0x7FFFu + ((u >> 16) & 1u);          // RNE (inputs finite)
    return (unsigned short)(u >> 16);
}

#define GLL(gp, lp) __builtin_amdgcn_global_load_lds( \
    (const __attribute__((address_space(1))) unsigned int*)(gp), \
    (__attribute__((address_space(3))) unsigned int*)(lp), 16, 0, 0)

// ---------------- x f32 -> bf16 (12 MB traffic; result L2/L3-resident) ----------------
__global__ __launch_bounds__(256) void conv_kernel(const float* __restrict__ x,
                                                   unsigned short* __restrict__ xb) {
    const int base = blockIdx.x * 1024 + threadIdx.x;
#pragma unroll
    for (int i = 0; i < 4; ++i) {
        const int cid = base + i * 256;               // 8-float chunk id
        const f32x4 a = *(const f32x4*)(x + (size_t)cid * 8);
        const f32x4 b = *(const f32x4*)(x + (size_t)cid * 8 + 4);
        u16x8 v;
        v[0] = f2bf(a[0]); v[1] = f2bf(a[1]); v[2] = f2bf(a[2]); v[3] = f2bf(a[3]);
        v[4] = f2bf(b[0]); v[5] = f2bf(b[1]); v[6] = f2bf(b[2]); v[7] = f2bf(b[3]);
        *(u16x8*)(xb + (size_t)cid * 8) = v;
    }
}

// ---------------- fused GEMM + BN + Swish ----------------
// Block: M=256 x N=32, K=1024, BK=64 (16 steps). 4 waves stacked in M.
// A: [256][64] bf16 LDS x2, GLL w/ source pre-swizzle (c ^= r&7).
// B: [32][64] bf16 LDS x2, W f32 reg-ring depth 4 -> cvt -> swizzled ds_write.
__global__ __launch_bounds__(256, 2) void fused_kernel(
    const unsigned short* __restrict__ xb, const float* __restrict__ W,
    const float* __restrict__ gamma, const float* __restrict__ beta,
    float* __restrict__ out)
{
    __shared__ __align__(16) char ldsA[2][32768];
    __shared__ __align__(16) char ldsB[2][4096];
    __shared__ float wps1[4][32], wps2[4][32];
    __shared__ float sa[32], sb[32];

    const int bid = blockIdx.x;
    const int g   = bid & 7;               // channel group -> XCD
    const int nt  = bid >> 3;              // 0..31
    const int o   = g * 4 + (nt >> 3);
    const int f0  = (nt & 7) * 32;
    const int gcol0 = o * 256 + f0;

    const int t    = threadIdx.x;
    const int wave = t >> 6;
    const int lane = t & 63;
    const int lr   = lane & 15;
    const int kq   = lane >> 4;

    f32x4 acc[4][2];
    const f32x4 zero = {0.f, 0.f, 0.f, 0.f};
#pragma unroll
    for (int i = 0; i < 4; ++i) { acc[i][0] = zero; acc[i][1] = zero; }

    f32x4 breg[4][2];                      // W prefetch ring, depth 4

    auto ISSUE_W = [&](int st) {           // 2 loads (32B/thread), 8 thr per 64-k row slice
        const int cp = st >> 2, kc = (st & 3) * 64;
        const float* bsrc = W + ((size_t)((o * 32 + g * 4 + cp) * 256 + f0)) * 256 + kc
                              + (size_t)(t >> 3) * 256 + (t & 7) * 8;
        breg[st & 3][0] = *(const f32x4*)bsrc;
        breg[st & 3][1] = *(const f32x4*)(bsrc + 4);
    };
    auto ISSUE_A = [&](int st) {           // 8 GLL (16B) per thread, source pre-swizzled
        const unsigned short* asrc = xb + g * 1024 + st * 64;
        char* Ab = ldsA[st & 1];
#pragma unroll
        for (int i = 0; i < 8; ++i) {
            const int cid = i * 256 + t;
            const int r = cid >> 3, c = cid & 7;
            GLL(asrc + (size_t)r * 8192 + (c ^ (r & 7)) * 8, Ab + cid * 16);
        }
    };
    auto WRITEB = [&](int st) {            // cvt + swizzled ds_write (regs long since landed)
        const int n = t >> 3, c = t & 7;
        short8 v;
        v[0] = (short)f2bf(breg[st & 3][0][0]); v[1] = (short)f2bf(breg[st & 3][0][1]);
        v[2] = (short)f2bf(breg[st & 3][0][2]); v[3] = (short)f2bf(breg[st & 3][0][3]);
        v[4] = (short)f2bf(breg[st & 3][1][0]); v[5] = (short)f2bf(breg[st & 3][1][1]);
        v[6] = (short)f2bf(breg[st & 3][1][2]); v[7] = (short)f2bf(breg[st & 3][1][3]);
        *(short8*)(ldsB[st & 1] + n * 128 + ((c ^ (n & 7)) * 16)) = v;
    };
    auto COMPUTE = [&](int st) {
        const char* Ab = ldsA[st & 1];
        const char* Bb = ldsB[st & 1];
#pragma unroll
        for (int ks = 0; ks < 2; ++ks) {
            short8 af[4], bfr[2];
#pragma unroll
            for (int i = 0; i < 4; ++i) {
                const int ra = wave * 64 + i * 16 + lr;
                af[i] = *(const short8*)(Ab + ra * 128 + (((ks * 4 + kq) ^ (ra & 7)) * 16));
            }
#pragma unroll
            for (int j = 0; j < 2; ++j) {
                const int n = j * 16 + lr;
                bfr[j] = *(const short8*)(Bb + n * 128 + (((ks * 4 + kq) ^ (n & 7)) * 16));
            }
#pragma unroll
            for (int i = 0; i < 4; ++i)
#pragma unroll
                for (int j = 0; j < 2; ++j)
                    acc[i][j] = __builtin_amdgcn_mfma_f32_16x16x32_bf16(af[i], bfr[j], acc[i][j], 0, 0, 0);
        }
    };

    // prologue: W(0), A(0), W(1..3) issued; B0 written; drain A(0), keep W(1..3)
    ISSUE_W(0);
    ISSUE_A(0);
    ISSUE_W(1);
    ISSUE_W(2);
    ISSUE_W(3);
    WRITEB(0);                                         // compiler waits W(0) only
    asm volatile("s_waitcnt vmcnt(6)" ::: "memory");   // A(0) done; W(1..3) in flight
    asm volatile("s_waitcnt lgkmcnt(0)" ::: "memory");
    __builtin_amdgcn_s_barrier();

#pragma unroll
    for (int st = 0; st < 16; ++st) {
        COMPUTE(st);                                   // readers: parity st
        if (st < 15) {
            ISSUE_A(st + 1);                           // writers: parity st+1
            if (st < 12) ISSUE_W(st + 4);
            WRITEB(st + 1);                            // W(st+1) landed iters ago
            if (st < 12) {
                asm volatile("s_waitcnt vmcnt(2)" ::: "memory");  // drain A(st+1); keep W(st+4)
            } else {
                asm volatile("s_waitcnt vmcnt(0)" ::: "memory");  // tail: nothing newer
            }
            asm volatile("s_waitcnt lgkmcnt(0)" ::: "memory");
            __builtin_amdgcn_s_barrier();
        }
    }

    // ---------------- fused BN + Swish epilogue ----------------
    float s1[2] = {0.f, 0.f}, s2[2] = {0.f, 0.f};
#pragma unroll
    for (int i = 0; i < 4; ++i)
#pragma unroll
        for (int j = 0; j < 2; ++j)
#pragma unroll
            for (int r = 0; r < 4; ++r) {
                const float v = acc[i][j][r];
                s1[j] += v; s2[j] += v * v;
            }
#pragma unroll
    for (int j = 0; j < 2; ++j) {          // reduce across kq groups (lanes sharing lr)
        s1[j] += __shfl_xor(s1[j], 16); s2[j] += __shfl_xor(s2[j], 16);
        s1[j] += __shfl_xor(s1[j], 32); s2[j] += __shfl_xor(s2[j], 32);
    }
    if (kq == 0) {
#pragma unroll
        for (int j = 0; j < 2; ++j) {
            wps1[wave][j * 16 + lr] = s1[j];
            wps2[wave][j * 16 + lr] = s2[j];
        }
    }
    __syncthreads();
    if (t < 32) {
        float a1 = wps1[0][t] + wps1[1][t] + wps1[2][t] + wps1[3][t];
        float a2 = wps2[0][t] + wps2[1][t] + wps2[2][t] + wps2[3][t];
        const float mean = a1 * (1.0f / 256.0f);
        const float var  = a2 * (1.0f / 256.0f) - mean * mean;   // biased (jnp.var)
        const float istd = rsqrtf(var + 1e-5f);
        const float ga = gamma[gcol0 + t];
        sa[t] = ga * istd;
        sb[t] = beta[gcol0 + t] - mean * ga * istd;
    }
    __syncthreads();

    // apply affine + swish; C/D layout col=lane&15, row=(lane>>4)*4+reg
#pragma unroll
    for (int i = 0; i < 4; ++i) {
        const int row0 = wave * 64 + i * 16 + kq * 4;
#pragma unroll
        for (int j = 0; j < 2; ++j) {
            const int col = j * 16 + lr;
            const float a = sa[col], b2 = sb[col];
#pragma unroll
            for (int r = 0; r < 4; ++r) {
                const float z = a * acc[i][j][r] + b2;
                out[(size_t)(row0 + r) * 8192 + gcol0 + col] = z / (1.0f + expf(-z));
            }
        }
    }
}

extern "C" void kernel_launch(void* const* d_in, const int* in_sizes, int n_in,
                              void* d_out, int out_size, void* d_ws, size_t ws_size,
                              hipStream_t stream) {
    const float* x     = (const float*)d_in[0];
    const float* W     = (const float*)d_in[1];
    // d_in[2] = bias: cancelled exactly by BN mean subtraction -> unused
    const float* gamma = (const float*)d_in[3];
    const float* beta  = (const float*)d_in[4];
    // d_in[5] = mask: implicit in block structure -> unused
    float* out = (float*)d_out;

    unsigned short* xb = (unsigned short*)d_ws;   // 4MB bf16 x

    conv_kernel<<<256, 256, 0, stream>>>(x, xb);
    fused_kernel<<<256, 256, 0, stream>>>(xb, W, gamma, beta, out);
}